// Round 3
// baseline (378.884 us; speedup 1.0000x reference)
//
#include <hip/hip_runtime.h>
#include <hip/hip_cooperative_groups.h>

namespace cg = cooperative_groups;

#define B_ 4
#define L_ 4096
#define D_ 64
#define N_ 16
#define CHUNK 16
#define NCHUNK (L_ / CHUNK)        // 256
#define TOTCHUNK (B_ * NCHUNK)     // 1024

constexpr float DT_  = 0.1f;
constexpr float EPS_ = 1e-6f;

// ===========================================================================
// FUSED cooperative kernel. 1024 blocks x 256 threads = exactly 4 blocks/CU
// (launch_bounds(256,4) => VGPR<=128, LDS 14.2KB => co-residency guaranteed).
//
// Key algebraic restructure: a[s,n] = exp(An*delta_s)  =>  decay products are
// exp(An*(Ds[s]-Ds[j])) with Ds = prefix-sum(delta). The serial 16-step scan
// becomes dense 16x16 matrices:
//   out_local = M @ x_chunk,   M[s,j] = sum_n cm[s,n]*exp(An*(Ds-Dj))*g[j,n]
//   S_local   = Wnj @ x_chunk, Wnj[j,n] = exp(An*(Ds15-Dsj))*g[j,n]
//   Wcor[s,n] = cm[s,n]*exp(An*Ds[s])   (kept in LDS across grid.sync)
//   Cdec[n]   = exp(An*Ds15)
// All exponents <= 0 -> no overflow. No serial scan chain, no out RMW
// (local out lives in 4 registers through both grid syncs), no Wcor global
// round-trip.
// ===========================================================================
__global__ __launch_bounds__(256, 4) void fused_kernel(
    const float* __restrict__ x,  const float* __restrict__ A,
    const float* __restrict__ Wb, const float* __restrict__ bb,
    const float* __restrict__ Wc, const float* __restrict__ bc,
    const float* __restrict__ Wd, const float* __restrict__ bd,
    float* __restrict__ S, float* __restrict__ Cdec,
    float* __restrict__ out)
{
    cg::grid_group grid = cg::this_grid();
    const int gc    = blockIdx.x;              // global chunk 0..1023
    const int batch = gc >> 8;
    const int c     = gc & (NCHUNK - 1);
    const int tid   = threadIdx.x;
    const int w     = tid >> 6;                // wave 0..3
    const int lane  = tid & 63;
    const int base0 = batch * L_ + c * CHUNK;

    __shared__ float xs[CHUNK * D_];           // 4 KB
    __shared__ float AnS[N_];
    __shared__ float dl[CHUNK];                // per-step delta
    __shared__ float DsS[CHUNK];               // prefix sums of delta
    __shared__ float bmS[CHUNK * N_];          // 1 KB  Bm[s][n]
    __shared__ float cmS[CHUNK * N_];          // 1 KB  Cm[s][n]
    __shared__ float gT[N_ * CHUNK];           // 1 KB  g[n][j]  (transposed)
    __shared__ float uS[CHUNK * N_];           // 1 KB  Wcor[s][n]
    __shared__ float wnjS[CHUNK * N_];         // 1 KB  Wnj[j][n]
    __shared__ float MS[CHUNK * CHUNK];        // 1 KB  M[s][j]
    __shared__ float his[N_ * D_];             // 4 KB  chunk-initial state

    // ---- stage x (256 float4, one per thread) + A row ----
    ((float4*)xs)[tid] = ((const float4*)(x + (size_t)base0 * D_))[tid];
    if (tid < N_) AnS[tid] = A[tid];           // rows of (D,N) identical

    // ---- W rows in registers (per-wave; overlaps staging latency) ----
    const int o  = lane & 31;                  // 0-15 -> Bm row, 16-31 -> Cm row
    const int h2 = lane >> 5;                  // K-half
    float wreg[32];
    const float* Wrow = (o < 16) ? (Wb + o * D_) : (Wc + (o - 16) * D_);
    const float4* w4p = (const float4*)(Wrow + h2 * 32);
    #pragma unroll
    for (int j = 0; j < 8; j++) {
        float4 w4 = w4p[j];
        wreg[4*j+0] = w4.x; wreg[4*j+1] = w4.y;
        wreg[4*j+2] = w4.z; wreg[4*j+3] = w4.w;
    }
    const float wd   = Wd[lane];
    const float bd0  = bd[0];
    const float bias = (o < 16) ? bb[o] : bc[o - 16];

    __syncthreads();

    // ---- deltas for this wave's 4 steps (s = 4w..4w+3) ----
    const int s0 = w * 4;
    float r[4];
    #pragma unroll
    for (int p = 0; p < 4; p++) r[p] = xs[(s0 + p) * D_ + lane] * wd;
    #pragma unroll
    for (int m = 32; m >= 1; m >>= 1) {
        #pragma unroll
        for (int p = 0; p < 4; p++) r[p] += __shfl_xor(r[p], m, 64);
    }
    #pragma unroll
    for (int p = 0; p < 4; p++) {
        float z = r[p] + bd0;
        float dlt = fmaxf(z, 0.0f) + log1pf(expf(-fabsf(z))) + DT_;
        if (lane == 0) dl[s0 + p] = dlt;
    }

    // ---- Bm/Cm dots for this wave's 4 steps -> LDS ----
    #pragma unroll
    for (int p = 0; p < 4; p++) {
        const int s = s0 + p;
        float acc = 0.0f;
        const float4* xs4 = (const float4*)(xs + s * D_ + h2 * 32);
        #pragma unroll
        for (int j = 0; j < 8; j++) {
            float4 v = xs4[j];                 // broadcast LDS reads
            acc += v.x * wreg[4*j+0] + v.y * wreg[4*j+1]
                 + v.z * wreg[4*j+2] + v.w * wreg[4*j+3];
        }
        acc += __shfl_xor(acc, 32, 64);        // lanes 0-31 hold full dots
        if (lane < 16)      bmS[s * 16 + lane]        = acc + bias;
        else if (lane < 32) cmS[s * 16 + (lane - 16)] = acc + bias;
    }
    __syncthreads();

    // ---- per-(s,n) phase: one thread per cell ----
    {
        const int s = tid >> 4, n = tid & 15;
        float ds = 0.0f, dsF = 0.0f;
        #pragma unroll
        for (int k = 0; k < CHUNK; k++) {
            float v = dl[k];
            dsF += v;
            if (k <= s) ds += v;
        }
        const float An  = AnS[n];
        const float dls = dl[s];
        const float tmp = An * dls;
        const float a   = expf(tmp);
        const float g   = (a - 1.0f) * dls * bmS[tid] / (tmp + EPS_);
        gT[n * 16 + s]  = g;                          // transposed for M build
        uS[tid]         = cmS[tid] * expf(An * ds);   // Wcor[s][n]
        wnjS[tid]       = expf(An * (dsF - ds)) * g;  // Wnj[j=s][n]
        if (n == 0) DsS[s] = ds;
        if (tid < 16) Cdec[gc * N_ + tid] = expf(AnS[tid] * dsF);
    }
    __syncthreads();

    // ---- M build: thread (s,j) does a 16-term n-sum (16 exps, all <=0) ----
    {
        const int s = tid >> 4, j = tid & 15;
        float m = 0.0f;
        if (j <= s) {
            const float dd = DsS[s] - DsS[j];         // >= 0
            #pragma unroll
            for (int n = 0; n < N_; n++)
                m += cmS[s * 16 + n] * expf(AnS[n] * dd) * gT[n * 16 + j];
        }
        MS[tid] = m;
    }
    __syncthreads();

    // ---- two 16x16 @ 16x64 GEMMs: out_local (regs) and S_local (global) ----
    const int d = lane;
    float oreg[4];
    #pragma unroll
    for (int k = 0; k < 4; k++) {
        const int sn = w * 4 + k;                     // doubles as s and n
        float acc = 0.0f, acc2 = 0.0f;
        #pragma unroll
        for (int j = 0; j < CHUNK; j++) {
            const float xv = xs[j * 64 + d];
            acc  += MS[sn * 16 + j]   * xv;           // M row: wave-uniform bcast
            acc2 += wnjS[j * 16 + sn] * xv;           // Wnj col: scalar bcast
        }
        oreg[k] = acc;                                // local (zero-init) output
        S[(size_t)(gc * N_ + sn) * D_ + d] = acc2;    // chunk-final local state
    }

    grid.sync();

    // ---- Phase B: cross-chunk exclusive scan (64 blocks, wave 0 only) ----
#define G2 16
    if (blockIdx.x < B_ * N_ && tid < 64) {
        const int b = blockIdx.x >> 4;
        const int n = blockIdx.x & 15;
        float*       baseS = S    + (size_t)((b * NCHUNK) * N_ + n) * D_ + lane;
        const float* baseA = Cdec + (b * NCHUNK) * N_ + n;

        float run = 0.0f;
        float sbuf[G2], abuf[G2];
        #pragma unroll
        for (int j = 0; j < G2; j++) {
            sbuf[j] = baseS[(size_t)j * (N_ * D_)];
            abuf[j] = baseA[j * N_];
        }
        for (int cc = 0; cc < NCHUNK; cc += G2) {
            const int cn = (cc + G2 < NCHUNK) ? (cc + G2) : cc;  // last: dummy
            float t[G2], u[G2];
            #pragma unroll
            for (int j = 0; j < G2; j++) {
                t[j] = baseS[(size_t)(cn + j) * (N_ * D_)];
                u[j] = baseA[(cn + j) * N_];
            }
            #pragma unroll
            for (int j = 0; j < G2; j++) {
                baseS[(size_t)(cc + j) * (N_ * D_)] = run;       // exclusive
                run = abuf[j] * run + sbuf[j];
            }
            #pragma unroll
            for (int j = 0; j < G2; j++) { sbuf[j] = t[j]; abuf[j] = u[j]; }
        }
    }

    grid.sync();

    // ---- Phase C: out = out_local + Wcor @ hi  (Wcor still in LDS) ----
    ((float4*)his)[tid] = ((const float4*)(S + (size_t)gc * N_ * D_))[tid];
    __syncthreads();
    #pragma unroll
    for (int k = 0; k < 4; k++) {
        const int s = w * 4 + k;
        float corr = 0.0f;
        #pragma unroll
        for (int n = 0; n < N_; n++)
            corr += uS[s * 16 + n] * his[n * 64 + d];
        out[(size_t)(base0 + s) * D_ + d] = oreg[k] + corr;
    }
}

// ===========================================================================
// FALLBACK path: round-2's proven 3-kernel pipeline (used only if cooperative
// launch is unavailable). Verbatim from the previous passing version.
// ===========================================================================
__global__ __launch_bounds__(256) void proj_scan_kernel(
    const float* __restrict__ x,  const float* __restrict__ A,
    const float* __restrict__ Wb, const float* __restrict__ bb,
    const float* __restrict__ Wc, const float* __restrict__ bc,
    const float* __restrict__ Wd, const float* __restrict__ bd,
    float* __restrict__ S, float* __restrict__ Cdec,
    float* __restrict__ Wcor, float* __restrict__ out)
{
    const int gc    = blockIdx.x;
    const int batch = gc >> 8;
    const int c     = gc & (NCHUNK - 1);
    const int tid   = threadIdx.x;
    const int w     = tid >> 6;
    const int lane  = tid & 63;
    const int base0 = batch * L_ + c * CHUNK;

    __shared__ float xs[CHUNK * D_];
    __shared__ float ag[CHUNK * 32];
    __shared__ float cm[CHUNK * N_];
    __shared__ float wbuf[CHUNK * N_];
    __shared__ float pout[4 * CHUNK * D_];

    ((float4*)xs)[tid] = ((const float4*)(x + (size_t)base0 * D_))[tid];

    const int o  = lane & 31;
    const int h2 = lane >> 5;
    float wreg[32];
    const float* Wrow = (o < 16) ? (Wb + o * D_) : (Wc + (o - 16) * D_);
    const float4* w4p = (const float4*)(Wrow + h2 * 32);
    #pragma unroll
    for (int j = 0; j < 8; j++) {
        float4 w4 = w4p[j];
        wreg[4*j+0] = w4.x; wreg[4*j+1] = w4.y;
        wreg[4*j+2] = w4.z; wreg[4*j+3] = w4.w;
    }
    const float wd   = Wd[lane];
    const float bd0  = bd[0];
    const float An   = A[lane & 15];
    const float bias = (o < 16) ? bb[o] : bc[o - 16];

    __syncthreads();

    const int s0 = w * 4;
    float r[4];
    #pragma unroll
    for (int p = 0; p < 4; p++) r[p] = xs[(s0 + p) * D_ + lane] * wd;
    #pragma unroll
    for (int m = 32; m >= 1; m >>= 1) {
        #pragma unroll
        for (int p = 0; p < 4; p++) r[p] += __shfl_xor(r[p], m, 64);
    }
    float delta[4];
    #pragma unroll
    for (int p = 0; p < 4; p++) {
        float z = r[p] + bd0;
        delta[p] = fmaxf(z, 0.0f) + log1pf(expf(-fabsf(z))) + DT_;
    }

    #pragma unroll
    for (int p = 0; p < 4; p++) {
        const int s = s0 + p;
        float acc = 0.0f;
        const float4* xs4 = (const float4*)(xs + s * D_ + h2 * 32);
        #pragma unroll
        for (int j = 0; j < 8; j++) {
            float4 v = xs4[j];
            acc += v.x * wreg[4*j+0] + v.y * wreg[4*j+1]
                 + v.z * wreg[4*j+2] + v.w * wreg[4*j+3];
        }
        acc += __shfl_xor(acc, 32, 64);
        if (lane < 16) {
            float Bm  = acc + bias;
            float tmp = An * delta[p];
            float a   = expf(tmp);
            float g   = (a - 1.0f) * delta[p] * Bm / (tmp + EPS_);
            ag[s * 32 + lane]      = a;
            ag[s * 32 + 16 + lane] = g;
        } else if (lane < 32) {
            cm[s * 16 + (lane - 16)] = acc + bias;
        }
    }
    __syncthreads();

    const int n0 = w * 4;
    float h0 = 0.0f, h1 = 0.0f, h2v = 0.0f, h3 = 0.0f;
    #pragma unroll
    for (int s = 0; s < CHUNK; s++) {
        float  xd = xs[s * D_ + lane];
        float4 a4 = *(const float4*)(ag + s * 32 + n0);
        float4 g4 = *(const float4*)(ag + s * 32 + 16 + n0);
        float4 c4 = *(const float4*)(cm + s * 16 + n0);
        h0 = a4.x * h0 + g4.x * xd;  float acc = c4.x * h0;
        h1 = a4.y * h1 + g4.y * xd;  acc += c4.y * h1;
        h2v = a4.z * h2v + g4.z * xd; acc += c4.z * h2v;
        h3 = a4.w * h3 + g4.w * xd;  acc += c4.w * h3;
        pout[(w * CHUNK + s) * D_ + lane] = acc;
    }
    S[(size_t)(gc * N_ + n0 + 0) * D_ + lane] = h0;
    S[(size_t)(gc * N_ + n0 + 1) * D_ + lane] = h1;
    S[(size_t)(gc * N_ + n0 + 2) * D_ + lane] = h2v;
    S[(size_t)(gc * N_ + n0 + 3) * D_ + lane] = h3;

    if (tid < 16) {
        float cumn = 1.0f;
        #pragma unroll
        for (int s = 0; s < CHUNK; s++) {
            cumn *= ag[s * 32 + tid];
            wbuf[s * 16 + tid] = cm[s * 16 + tid] * cumn;
        }
        Cdec[gc * N_ + tid] = cumn;
    }
    __syncthreads();

    #pragma unroll
    for (int k = 0; k < 4; k++) {
        const int f = k * 256 + tid;
        float v = pout[f] + pout[CHUNK * D_ + f]
                + pout[2 * CHUNK * D_ + f] + pout[3 * CHUNK * D_ + f];
        out[(size_t)base0 * D_ + f] = v;
    }
    if (tid < 64)
        ((float4*)(Wcor + (size_t)base0 * 16))[tid] = ((const float4*)wbuf)[tid];
}

#define G_ 32
__global__ __launch_bounds__(64) void combine(
    float* __restrict__ S, const float* __restrict__ Cdec)
{
    const int b = blockIdx.x >> 4;
    const int n = blockIdx.x & 15;
    const int d = threadIdx.x;
    const int cb = b * NCHUNK;

    float*       baseS = S    + (size_t)(cb * N_ + n) * D_ + d;
    const float* baseA = Cdec + cb * N_ + n;

    float run = 0.0f;
    float sbuf[G_], abuf[G_];
    #pragma unroll
    for (int j = 0; j < G_; j++) {
        sbuf[j] = baseS[(size_t)j * (N_ * D_)];
        abuf[j] = baseA[j * N_];
    }
    for (int cc = 0; cc < NCHUNK; cc += G_) {
        const int cn = (cc + G_ < NCHUNK) ? (cc + G_) : cc;
        float t[G_], u[G_];
        #pragma unroll
        for (int j = 0; j < G_; j++) {
            t[j] = baseS[(size_t)(cn + j) * (N_ * D_)];
            u[j] = baseA[(cn + j) * N_];
        }
        #pragma unroll
        for (int j = 0; j < G_; j++) {
            baseS[(size_t)(cc + j) * (N_ * D_)] = run;
            run = abuf[j] * run + sbuf[j];
        }
        #pragma unroll
        for (int j = 0; j < G_; j++) { sbuf[j] = t[j]; abuf[j] = u[j]; }
    }
}

__global__ __launch_bounds__(256) void apply_kernel(
    const float* __restrict__ Wcor, const float* __restrict__ S,
    float* __restrict__ out)
{
    const int gc    = blockIdx.x;
    const int batch = gc >> 8;
    const int c     = gc & (NCHUNK - 1);
    const int tid   = threadIdx.x;
    const int w     = tid >> 6;
    const int lane  = tid & 63;
    const int base0 = batch * L_ + c * CHUNK;

    __shared__ float wl[CHUNK * N_];

    if (tid < 64)
        ((float4*)wl)[tid] = ((const float4*)(Wcor + (size_t)base0 * 16))[tid];

    float hi[N_];
    #pragma unroll
    for (int n = 0; n < N_; n++)
        hi[n] = S[(size_t)(gc * N_ + n) * D_ + lane];

    const int s0 = w * 4;
    float oreg[4];
    #pragma unroll
    for (int p = 0; p < 4; p++)
        oreg[p] = out[(size_t)(base0 + s0 + p) * D_ + lane];

    __syncthreads();

    #pragma unroll
    for (int p = 0; p < 4; p++) {
        const int s = s0 + p;
        const float4* crw = (const float4*)(wl + s * 16);
        float a = oreg[p];
        #pragma unroll
        for (int q = 0; q < 4; q++) {
            float4 w4 = crw[q];
            a += w4.x * hi[4*q+0] + w4.y * hi[4*q+1]
               + w4.z * hi[4*q+2] + w4.w * hi[4*q+3];
        }
        out[(size_t)(base0 + s) * D_ + lane] = a;
    }
}

// ---------------------------------------------------------------------------
extern "C" void kernel_launch(void* const* d_in, const int* in_sizes, int n_in,
                              void* d_out, int out_size, void* d_ws, size_t ws_size,
                              hipStream_t stream)
{
    const float* x  = (const float*)d_in[0];
    const float* A  = (const float*)d_in[1];
    const float* Wb = (const float*)d_in[2];
    const float* bb = (const float*)d_in[3];
    const float* Wc = (const float*)d_in[4];
    const float* bc = (const float*)d_in[5];
    const float* Wd = (const float*)d_in[6];
    const float* bd = (const float*)d_in[7];
    float* outp = (float*)d_out;

    // ws carve (floats): S 1048576 (4MB) | Cdec 16384 | Wcor 262144 (fallback)
    float* S    = (float*)d_ws;
    float* Cdec = S    + (size_t)TOTCHUNK * N_ * D_;
    float* Wcor = Cdec + (size_t)TOTCHUNK * N_;

    // cooperative-launch capability check (pure host query, capture-safe)
    int dev = 0, coop = 0;
    hipGetDevice(&dev);
    hipDeviceGetAttribute(&coop, hipDeviceAttributeCooperativeLaunch, dev);

    bool launched = false;
    if (coop) {
        void* args[] = { (void*)&x, (void*)&A, (void*)&Wb, (void*)&bb,
                         (void*)&Wc, (void*)&bc, (void*)&Wd, (void*)&bd,
                         (void*)&S, (void*)&Cdec, (void*)&outp };
        hipError_t err = hipLaunchCooperativeKernel(
            (const void*)fused_kernel, dim3(TOTCHUNK), dim3(256),
            args, 0, stream);
        launched = (err == hipSuccess);
    }

    if (!launched) {
        proj_scan_kernel<<<TOTCHUNK, 256, 0, stream>>>(x, A, Wb, bb, Wc, bc,
                                                       Wd, bd, S, Cdec, Wcor,
                                                       outp);
        combine<<<B_ * N_, 64, 0, stream>>>(S, Cdec);
        apply_kernel<<<TOTCHUNK, 256, 0, stream>>>(Wcor, S, outp);
    }
}

// Round 4
// 100.722 us; speedup vs baseline: 3.7617x; 3.7617x over previous
//
#include <hip/hip_runtime.h>

#define B_ 4
#define L_ 4096
#define D_ 64
#define N_ 16
#define CHUNK 16
#define NCHUNK (L_ / CHUNK)        // 256
#define TOTCHUNK (B_ * NCHUNK)     // 1024

constexpr float DT_  = 0.1f;
constexpr float EPS_ = 1e-6f;

// ---------------------------------------------------------------------------
// K1: fused projection + DENSE-MATRIX chunk scan (algebra verified in the
// round-3 cooperative kernel, which passed correctness).
//   a[s,n] = exp(An*delta_s)  =>  decay products are exp(An*(Ds[s]-Ds[j]))
//   with Ds = prefix-sum(delta). So:
//     out_local = M @ x_chunk,   M[s,j] = sum_n cm[s,n]*exp(An*(Ds-Dj))*g[j,n]
//     S_local   = Wnj @ x_chunk, Wnj[j,n] = exp(An*(Ds15-Dsj))*g[j,n]
//     Wcor[s,n] = cm[s,n]*exp(An*Ds[s]),  Cdec[n] = exp(An*Ds15)
//   All exponents <= 0 -> no overflow. NO serial scan chain, NO 16KB pout
//   reduction buffer (LDS 24KB -> ~10.5KB), out written straight from GEMM.
// 1024 blocks x 256 threads (4 waves), plain 3-dispatch pipeline.
// ---------------------------------------------------------------------------
__global__ __launch_bounds__(256) void proj_scan_kernel(
    const float* __restrict__ x,  const float* __restrict__ A,
    const float* __restrict__ Wb, const float* __restrict__ bb,
    const float* __restrict__ Wc, const float* __restrict__ bc,
    const float* __restrict__ Wd, const float* __restrict__ bd,
    float* __restrict__ S, float* __restrict__ Cdec,
    float* __restrict__ Wcor, float* __restrict__ out)
{
    const int gc    = blockIdx.x;              // global chunk 0..1023
    const int batch = gc >> 8;
    const int c     = gc & (NCHUNK - 1);
    const int tid   = threadIdx.x;
    const int w     = tid >> 6;                // wave 0..3
    const int lane  = tid & 63;
    const int base0 = batch * L_ + c * CHUNK;

    __shared__ float xs[CHUNK * D_];           // 4 KB
    __shared__ float AnS[N_];
    __shared__ float dl[CHUNK];                // per-step delta
    __shared__ float DsS[CHUNK];               // prefix sums of delta
    __shared__ float bmS[CHUNK * N_];          // 1 KB  Bm[s][n]
    __shared__ float cmS[CHUNK * N_];          // 1 KB  Cm[s][n]
    __shared__ float gT[N_ * CHUNK];           // 1 KB  g[n][j]  (transposed)
    __shared__ float uS[CHUNK * N_];           // 1 KB  Wcor[s][n]
    __shared__ float wnjS[CHUNK * N_];         // 1 KB  Wnj[j][n]
    __shared__ float MS[CHUNK * CHUNK];        // 1 KB  M[s][j]

    // ---- stage x (256 float4, one per thread) + A row ----
    ((float4*)xs)[tid] = ((const float4*)(x + (size_t)base0 * D_))[tid];
    if (tid < N_) AnS[tid] = A[tid];           // rows of (D,N) identical

    // ---- W rows in registers (per-wave; overlaps staging latency) ----
    const int o  = lane & 31;                  // 0-15 -> Bm row, 16-31 -> Cm row
    const int h2 = lane >> 5;                  // K-half
    float wreg[32];
    const float* Wrow = (o < 16) ? (Wb + o * D_) : (Wc + (o - 16) * D_);
    const float4* w4p = (const float4*)(Wrow + h2 * 32);
    #pragma unroll
    for (int j = 0; j < 8; j++) {
        float4 w4 = w4p[j];
        wreg[4*j+0] = w4.x; wreg[4*j+1] = w4.y;
        wreg[4*j+2] = w4.z; wreg[4*j+3] = w4.w;
    }
    const float wd   = Wd[lane];
    const float bd0  = bd[0];
    const float bias = (o < 16) ? bb[o] : bc[o - 16];

    __syncthreads();

    // ---- deltas for this wave's 4 steps (s = 4w..4w+3) ----
    const int s0 = w * 4;
    float r[4];
    #pragma unroll
    for (int p = 0; p < 4; p++) r[p] = xs[(s0 + p) * D_ + lane] * wd;
    #pragma unroll
    for (int m = 32; m >= 1; m >>= 1) {
        #pragma unroll
        for (int p = 0; p < 4; p++) r[p] += __shfl_xor(r[p], m, 64);
    }
    #pragma unroll
    for (int p = 0; p < 4; p++) {
        float z = r[p] + bd0;
        float dlt = fmaxf(z, 0.0f) + log1pf(expf(-fabsf(z))) + DT_;
        if (lane == 0) dl[s0 + p] = dlt;
    }

    // ---- Bm/Cm dots for this wave's 4 steps -> LDS ----
    #pragma unroll
    for (int p = 0; p < 4; p++) {
        const int s = s0 + p;
        float acc = 0.0f;
        const float4* xs4 = (const float4*)(xs + s * D_ + h2 * 32);
        #pragma unroll
        for (int j = 0; j < 8; j++) {
            float4 v = xs4[j];                 // broadcast LDS reads
            acc += v.x * wreg[4*j+0] + v.y * wreg[4*j+1]
                 + v.z * wreg[4*j+2] + v.w * wreg[4*j+3];
        }
        acc += __shfl_xor(acc, 32, 64);        // lanes 0-31 hold full dots
        if (lane < 16)      bmS[s * 16 + lane]        = acc + bias;
        else if (lane < 32) cmS[s * 16 + (lane - 16)] = acc + bias;
    }
    __syncthreads();

    // ---- per-(s,n) phase: one thread per cell ----
    {
        const int s = tid >> 4, n = tid & 15;
        float ds = 0.0f, dsF = 0.0f;
        #pragma unroll
        for (int k = 0; k < CHUNK; k++) {
            float v = dl[k];
            dsF += v;
            if (k <= s) ds += v;
        }
        const float An  = AnS[n];
        const float dls = dl[s];
        const float tmp = An * dls;
        const float a   = expf(tmp);
        const float g   = (a - 1.0f) * dls * bmS[tid] / (tmp + EPS_);
        gT[n * 16 + s]  = g;                          // transposed for M build
        uS[tid]         = cmS[tid] * expf(An * ds);   // Wcor[s][n]
        wnjS[tid]       = expf(An * (dsF - ds)) * g;  // Wnj[j=s][n]
        if (n == 0) DsS[s] = ds;
        if (tid < 16) Cdec[gc * N_ + tid] = expf(AnS[tid] * dsF);
    }
    __syncthreads();

    // ---- M build: thread (s,j) does a 16-term n-sum (16 exps, all <=0) ----
    {
        const int s = tid >> 4, j = tid & 15;
        float m = 0.0f;
        if (j <= s) {
            const float dd = DsS[s] - DsS[j];         // >= 0
            #pragma unroll
            for (int n = 0; n < N_; n++)
                m += cmS[s * 16 + n] * expf(AnS[n] * dd) * gT[n * 16 + j];
        }
        MS[tid] = m;
    }
    __syncthreads();

    // ---- two 16x16 @ 16x64 GEMMs: out_local and S_local ----
    const int d = lane;
    #pragma unroll
    for (int k = 0; k < 4; k++) {
        const int sn = w * 4 + k;                     // doubles as s and n
        float acc = 0.0f, acc2 = 0.0f;
        #pragma unroll
        for (int j = 0; j < CHUNK; j++) {
            const float xv = xs[j * 64 + d];
            acc  += MS[sn * 16 + j]   * xv;           // M row: wave-uniform bcast
            acc2 += wnjS[j * 16 + sn] * xv;           // Wnj col: bcast
        }
        out[(size_t)(base0 + sn) * D_ + d] = acc;     // local (zero-init) output
        S[(size_t)(gc * N_ + sn) * D_ + d] = acc2;    // chunk-final local state
    }

    // ---- coalesced blast of Wcor (256 floats = 64 float4) ----
    if (tid < 64)
        ((float4*)(Wcor + (size_t)base0 * 16))[tid] = ((const float4*)uS)[tid];
}

// ---------------------------------------------------------------------------
// K2: cross-chunk exclusive scan, 64 blocks x 64 threads; block = (b,n),
// thread = d. Groups of 32 with next-group prefetch: 64 loads in flight while
// a group's serial chain runs. (Round-0 proven config.)
// ---------------------------------------------------------------------------
#define G_ 32
__global__ __launch_bounds__(64) void combine(
    float* __restrict__ S, const float* __restrict__ Cdec)
{
    const int b = blockIdx.x >> 4;
    const int n = blockIdx.x & 15;
    const int d = threadIdx.x;
    const int cb = b * NCHUNK;

    float*       baseS = S    + (size_t)(cb * N_ + n) * D_ + d;  // stride N_*D_ per chunk
    const float* baseA = Cdec + cb * N_ + n;                     // stride N_ per chunk

    float run = 0.0f;
    float sbuf[G_], abuf[G_];
    #pragma unroll
    for (int j = 0; j < G_; j++) {
        sbuf[j] = baseS[(size_t)j * (N_ * D_)];
        abuf[j] = baseA[j * N_];
    }
    for (int cc = 0; cc < NCHUNK; cc += G_) {
        const int cn = (cc + G_ < NCHUNK) ? (cc + G_) : cc;   // last: dummy reload
        float t[G_], u[G_];
        #pragma unroll
        for (int j = 0; j < G_; j++) {
            t[j] = baseS[(size_t)(cn + j) * (N_ * D_)];
            u[j] = baseA[(cn + j) * N_];
        }
        #pragma unroll
        for (int j = 0; j < G_; j++) {
            baseS[(size_t)(cc + j) * (N_ * D_)] = run;        // exclusive prefix
            run = abuf[j] * run + sbuf[j];
        }
        #pragma unroll
        for (int j = 0; j < G_; j++) { sbuf[j] = t[j]; abuf[j] = u[j]; }
    }
}

// ---------------------------------------------------------------------------
// K3: apply correction: out[l,d] += sum_n Wcor_l[n] * hi[n,d].
// 1024 blocks x 256 threads. hi staged ONCE through LDS (1 float4/thread =
// 4KB/block) instead of round-2's 4x-redundant 16 scalar loads per thread.
// All global loads issued before the sync so their latencies overlap.
// ---------------------------------------------------------------------------
__global__ __launch_bounds__(256) void apply_kernel(
    const float* __restrict__ Wcor, const float* __restrict__ S,
    float* __restrict__ out)
{
    const int gc    = blockIdx.x;
    const int batch = gc >> 8;
    const int c     = gc & (NCHUNK - 1);
    const int tid   = threadIdx.x;
    const int w     = tid >> 6;
    const int lane  = tid & 63;
    const int base0 = batch * L_ + c * CHUNK;

    __shared__ float wl[CHUNK * N_];           // 1 KB
    __shared__ float his[N_ * D_];             // 4 KB

    // stage chunk-initial state (post-combine S): 256 float4, one per thread
    ((float4*)his)[tid] = ((const float4*)(S + (size_t)gc * N_ * D_))[tid];

    // stage correction matrix (256 floats = 64 float4)
    if (tid < 64)
        ((float4*)wl)[tid] = ((const float4*)(Wcor + (size_t)base0 * 16))[tid];

    // prefetch this wave's 4 out rows
    const int s0 = w * 4;
    float oreg[4];
    #pragma unroll
    for (int p = 0; p < 4; p++)
        oreg[p] = out[(size_t)(base0 + s0 + p) * D_ + lane];

    __syncthreads();

    #pragma unroll
    for (int p = 0; p < 4; p++) {
        const int s = s0 + p;
        float a = oreg[p];
        #pragma unroll
        for (int n = 0; n < N_; n++)
            a += wl[s * 16 + n] * his[n * 64 + lane];   // bcast * conflict-free
        out[(size_t)(base0 + s) * D_ + lane] = a;
    }
}

// ---------------------------------------------------------------------------
extern "C" void kernel_launch(void* const* d_in, const int* in_sizes, int n_in,
                              void* d_out, int out_size, void* d_ws, size_t ws_size,
                              hipStream_t stream)
{
    const float* x  = (const float*)d_in[0];
    const float* A  = (const float*)d_in[1];
    const float* Wb = (const float*)d_in[2];
    const float* bb = (const float*)d_in[3];
    const float* Wc = (const float*)d_in[4];
    const float* bc = (const float*)d_in[5];
    const float* Wd = (const float*)d_in[6];
    const float* bd = (const float*)d_in[7];
    float* out = (float*)d_out;

    // ws carve (floats): S 1048576 (4MB) | Cdec 16384 | Wcor 262144 (1MB)
    float* S    = (float*)d_ws;
    float* Cdec = S    + (size_t)TOTCHUNK * N_ * D_;
    float* Wcor = Cdec + (size_t)TOTCHUNK * N_;

    proj_scan_kernel<<<TOTCHUNK, 256, 0, stream>>>(x, A, Wb, bb, Wc, bc, Wd, bd,
                                                   S, Cdec, Wcor, out);
    combine<<<B_ * N_, 64, 0, stream>>>(S, Cdec);
    apply_kernel<<<TOTCHUNK, 256, 0, stream>>>(Wcor, S, out);
}